// Round 4
// baseline (80.518 us; speedup 1.0000x reference)
//
#include <hip/hip_runtime.h>
#include <math.h>

#define CIN   128
#define COUT  128
#define PPC   8128              /* COUT*(COUT-1)/2 */
#define NFLT  (CIN*COUT*9)

// ---------------- helpers ----------------

__device__ inline void decode_pair(int p, int& a, int& b) {
    int a0 = (int)((255.0f - sqrtf((float)(65025 - 8 * p))) * 0.5f);
    if (a0 < 0) a0 = 0;
    if (a0 > 126) a0 = 126;
    while ((a0 + 1) * (255 - (a0 + 1)) / 2 <= p) ++a0;
    while (a0 * (255 - a0) / 2 > p) --a0;
    a = a0;
    b = a0 + 1 + (p - a0 * (255 - a0) / 2);
}

// reflect-pad 3x3 gaussian blur = A·X·A^T, A = [[g1,2g0,0],[g0,g1,g0],[0,2g0,g1]]
__device__ inline void blur3f(const float* X, float* O, float g0, float g1) {
    float h0 = 2.0f * g0;
    float T[9];
#pragma unroll
    for (int c = 0; c < 3; ++c) {
        float x0 = X[c], x1 = X[3 + c], x2 = X[6 + c];
        T[c]     = g1 * x0 + h0 * x1;
        T[3 + c] = g0 * (x0 + x2) + g1 * x1;
        T[6 + c] = h0 * x1 + g1 * x2;
    }
#pragma unroll
    for (int r = 0; r < 3; ++r) {
        float t0 = T[3 * r], t1 = T[3 * r + 1], t2 = T[3 * r + 2];
        O[3 * r]     = g1 * t0 + h0 * t1;
        O[3 * r + 1] = g0 * (t0 + t2) + g1 * t1;
        O[3 * r + 2] = h0 * t1 + g1 * t2;
    }
}

__device__ inline void blur3d(const double* X, double* O, double g0, double g1) {
    double h0 = 2.0 * g0;
    double T[9];
#pragma unroll
    for (int c = 0; c < 3; ++c) {
        double x0 = X[c], x1 = X[3 + c], x2 = X[6 + c];
        T[c]     = g1 * x0 + h0 * x1;
        T[3 + c] = g0 * (x0 + x2) + g1 * x1;
        T[6 + c] = h0 * x1 + g1 * x2;
    }
#pragma unroll
    for (int r = 0; r < 3; ++r) {
        double t0 = T[3 * r], t1 = T[3 * r + 1], t2 = T[3 * r + 2];
        O[3 * r]     = g1 * t0 + h0 * t1;
        O[3 * r + 1] = g0 * (t0 + t2) + g1 * t1;
        O[3 * r + 2] = h0 * t1 + g1 * t2;
    }
}

// ---------------- kernel 1: global min/max (per-block slots) + zero accumulators ----------------

__global__ __launch_bounds__(256) void k_minmax(const float* __restrict__ in,
                                                float* __restrict__ pbmin,
                                                float* __restrict__ pbmax,
                                                float* __restrict__ segsum,
                                                float* __restrict__ segcnt,
                                                unsigned* __restrict__ done) {
    int tid = threadIdx.x;
    float lmin = 1e30f, lmax = -1e30f;
    for (int i = blockIdx.x * 256 + tid; i < NFLT; i += 64 * 256) {
        float v = in[i];
        lmin = fminf(lmin, v);
        lmax = fmaxf(lmax, v);
    }
#pragma unroll
    for (int o = 32; o > 0; o >>= 1) {
        lmin = fminf(lmin, __shfl_down(lmin, o));
        lmax = fmaxf(lmax, __shfl_down(lmax, o));
    }
    __shared__ float rmn[4], rmx[4];
    if ((tid & 63) == 0) { rmn[tid >> 6] = lmin; rmx[tid >> 6] = lmax; }
    __syncthreads();
    if (tid == 0) {
        pbmin[blockIdx.x] = fminf(fminf(rmn[0], rmn[1]), fminf(rmn[2], rmn[3]));
        pbmax[blockIdx.x] = fmaxf(fmaxf(rmx[0], rmx[1]), fmaxf(rmx[2], rmx[3]));
    }
    if (blockIdx.x == 0) {
        if (tid < 128)       { segsum[tid] = 0.0f; segcnt[tid] = 0.0f; }
        else if (tid == 128) { *done = 0u; }
    }
}

// ---------------- kernel 2: everything else (2 blocks per channel, last block finalizes) ----------------

__global__ __launch_bounds__(256) void k_main(const float* __restrict__ in,
                                              const float* __restrict__ pbmin,
                                              const float* __restrict__ pbmax,
                                              float* __restrict__ segsum,
                                              float* __restrict__ segcnt,
                                              unsigned* __restrict__ done,
                                              float* __restrict__ out,
                                              float g0f, float g1f,
                                              double g0, double g1) {
    __shared__ float  s32[COUT * 27];   // x[9], mu[9], s1[9] per map (stride 27, odd)
    __shared__ double s64[COUT * 19];   // mu[0..8], s1[9..17] per map (stride 19)
    __shared__ float  stg[COUT * 9];    // raw channel input
    __shared__ float  bs[128], bc[128]; // segment bins
    __shared__ float  cf[2];
    __shared__ double cd[2];
    __shared__ int    lastflag;

    int tid = threadIdx.x;
    int c = blockIdx.x >> 1, q = blockIdx.x & 1;

    // stage this channel's 128 maps (contiguous 1152 floats)
    const float* src = in + c * (COUT * 9);
    for (int i = tid; i < COUT * 9; i += 256) stg[i] = src[i];

    // reduce the 64 per-block min/max -> C1, C2
    if (tid < 64) {
        float mn = pbmin[tid], mx = pbmax[tid];
#pragma unroll
        for (int o = 32; o > 0; o >>= 1) {
            mn = fminf(mn, __shfl_down(mn, o));
            mx = fmaxf(mx, __shfl_down(mx, o));
        }
        if (tid == 0) {
            double rng = (double)mx - (double)mn;
            if (rng == 0.0) rng = 1.0;
            double C1 = (0.01 * rng) * (0.01 * rng);
            double C2 = (0.03 * rng) * (0.03 * rng);
            cd[0] = C1; cd[1] = C2;
            cf[0] = (float)C1; cf[1] = (float)C2;
        }
    }
    if (tid < 128) { bs[tid] = 0.0f; bc[tid] = 0.0f; }
    __syncthreads();

    // per-map precompute: thread t handles map t (f32 screen pack + f64 exact pack)
    if (tid < COUT) {
        float xf[9];
#pragma unroll
        for (int k = 0; k < 9; ++k) xf[k] = stg[tid * 9 + k];
        float mu[9], qq[9], bq[9];
        blur3f(xf, mu, g0f, g1f);
#pragma unroll
        for (int k = 0; k < 9; ++k) qq[k] = xf[k] * xf[k];
        blur3f(qq, bq, g0f, g1f);
        float* o = s32 + tid * 27;
#pragma unroll
        for (int k = 0; k < 9; ++k) {
            o[k]      = xf[k];
            o[9 + k]  = mu[k];
            o[18 + k] = bq[k] - mu[k] * mu[k];
        }
        double xd[9], mud[9], qd[9], bqd[9];
#pragma unroll
        for (int k = 0; k < 9; ++k) xd[k] = (double)xf[k];
        blur3d(xd, mud, g0, g1);
#pragma unroll
        for (int k = 0; k < 9; ++k) qd[k] = xd[k] * xd[k];
        blur3d(qd, bqd, g0, g1);
        double* od = s64 + tid * 19;
#pragma unroll
        for (int k = 0; k < 9; ++k) {
            od[k]     = mud[k];
            od[9 + k] = bqd[k] - mud[k] * mud[k];
        }
    }
    __syncthreads();

    float C1 = cf[0], C2 = cf[1];
    double C1d = cd[0], C2d = cd[1];

    for (int p = tid + 256 * q; p < PPC; p += 512) {
        int a, b;
        decode_pair(p, a, b);
        const float* A = s32 + a * 27;   // a ~wave-uniform -> broadcast
        const float* B = s32 + b * 27;   // consecutive b, stride 27 -> conflict-free

        float z[9], bz[9];
#pragma unroll
        for (int k = 0; k < 9; ++k) z[k] = A[k] * B[k];
        blur3f(z, bz, g0f, g1f);

        // sum of 9 fractions as one fused fraction: 1 divide
        float an = 0.0f, ad = 1.0f;
#pragma unroll
        for (int k = 0; k < 9; ++k) {
            float ma = A[9 + k], mb = B[9 + k];
            float mu12 = ma * mb;
            float s12  = bz[k] - mu12;
            float nn = fmaf(2.0f, mu12, C1) * fmaf(2.0f, s12, C2);
            float dd = fmaf(ma, ma, fmaf(mb, mb, C1)) * (A[18 + k] + B[18 + k] + C2);
            an = an * dd + nn * ad;
            ad *= dd;
        }
        float ssim = an / (ad * 9.0f);

        if (!(ssim <= 0.897f)) {          // screen (NaN-safe: non-finite goes exact)
            // exact fp64 recompute, identical op order to the bit-matching path
            const double* MA = s64 + a * 19;
            const double* MB = s64 + b * 19;
            double zd[9], bzd[9];
#pragma unroll
            for (int k = 0; k < 9; ++k) zd[k] = (double)A[k] * (double)B[k];
            blur3d(zd, bzd, g0, g1);
            double ssum = 0.0;
#pragma unroll
            for (int k = 0; k < 9; ++k) {
                double ma = MA[k], mb = MB[k];
                double mu12 = ma * mb;
                double s12  = bzd[k] - mu12;
                double num  = (2.0 * mu12 + C1d) * (2.0 * s12 + C2d);
                double den  = (ma * ma + mb * mb + C1d) * (MA[9 + k] + MB[9 + k] + C2d);
                ssum += num / den;
            }
            double hg = ssum / 9.0 - 0.9;
            if (hg > 0.0) {
                unsigned seg = (unsigned)(p * 128 + c) / 8128u;  // reference's mixed segments
                atomicAdd(&bs[seg], (float)hg);
                atomicAdd(&bc[seg], 1.0f);
            }
        }
    }
    __syncthreads();

    // flush bins to global
    if (tid < 128) {
        float s = bs[tid], n = bc[tid];
        if (s != 0.0f || n != 0.0f) {
            atomicAdd(&segsum[tid], s);
            atomicAdd(&segcnt[tid], n);
        }
        __threadfence();
    }
    __syncthreads();

    // last-block ticket -> finalize
    if (tid == 0) {
        unsigned t = atomicAdd(done, 1u);
        lastflag = (t == (unsigned)(gridDim.x - 1));
    }
    __syncthreads();
    if (lastflag) {
        double v = 0.0;
        if (tid < 128) {
            float s = atomicAdd(&segsum[tid], 0.0f);   // L2-fresh read
            float n = atomicAdd(&segcnt[tid], 0.0f);
            v = (double)s / fmax((double)n, 1.0);
        }
#pragma unroll
        for (int o = 32; o > 0; o >>= 1) v += __shfl_down(v, o);
        __shared__ double w2[2];
        if (tid < 128 && (tid & 63) == 0) w2[tid >> 6] = v;
        __syncthreads();
        if (tid == 0) out[0] = (float)((w2[0] + w2[1]) * (1.0 / 128.0));
    }
}

// ---------------- launch ----------------

extern "C" void kernel_launch(void* const* d_in, const int* in_sizes, int n_in,
                              void* d_out, int out_size, void* d_ws, size_t ws_size,
                              hipStream_t stream) {
    const float* in = (const float*)d_in[0];
    float* out = (float*)d_out;
    char* ws = (char*)d_ws;

    float*    pbmin  = (float*)(ws + 0);      // 64
    float*    pbmax  = (float*)(ws + 256);    // 64
    float*    segsum = (float*)(ws + 512);    // 128
    float*    segcnt = (float*)(ws + 1024);   // 128
    unsigned* done   = (unsigned*)(ws + 1536);

    double e = exp(-1.0 / 4.5);
    double s = 2.0 * e + 1.0;
    double g0 = e / s, g1 = 1.0 / s;
    float g0f = (float)g0, g1f = (float)g1;

    k_minmax<<<64, 256, 0, stream>>>(in, pbmin, pbmax, segsum, segcnt, done);
    k_main  <<<CIN * 2, 256, 0, stream>>>(in, pbmin, pbmax, segsum, segcnt, done, out,
                                          g0f, g1f, g0, g1);
}